// Round 1
// 632.180 us; speedup vs baseline: 1.2731x; 1.2731x over previous
//
#include <hip/hip_runtime.h>
#include <math.h>

// MoE router: N=16384 tokens, D=4096, E=64 experts, top-8.
// Kernel 1: logits = (x * (0.99 + 0.02*noise)) @ W -- f32, split-K x4 for occupancy
//   (was 1 block/CU -> 11.7% occupancy, latency-bound at 12% HBM).
// Kernel 2: thread-per-row softmax + biased top-8 in registers (replaces the
//   wave-serial shfl-butterfly version; E=64 fits in 64 VGPRs).

#define N_TOK 16384
#define DIM   4096
#define NEXP  64
#define TOPK  8

#define BM 64
#define BK 64
#define KSPLIT 4
#define KCHUNKS (DIM / (BK * KSPLIT))   // 16 chunks per block
#define XS_STRIDE 68                    // 64 + 4 pad, keeps 16B alignment

// ATOMIC_OUT=0: store partial[blockIdx.y][row][e] to workspace (no atomics)
// ATOMIC_OUT=1: atomicAdd into pre-zeroed logits (fallback if ws too small)
template<int ATOMIC_OUT>
__global__ __launch_bounds__(256) void gemm_logits_kernel(
    const float* __restrict__ x, const float* __restrict__ W,
    const float* __restrict__ noise, float* __restrict__ out)
{
    __shared__ float xs[BM * XS_STRIDE];  // 17408 B
    __shared__ float ws[BK * NEXP];       // 16384 B  -> 33792 B total, 4 blocks/CU

    const int t = threadIdx.x;
    const int rowBase = blockIdx.x * BM;
    const int kOff = blockIdx.y * (DIM / KSPLIT);   // split-K offset
    const int eg = t & 15;   // experts eg*4 .. eg*4+3
    const int rg = t >> 4;   // rows    rg*4 .. rg*4+3

    float acc[4][4];
#pragma unroll
    for (int m = 0; m < 4; ++m)
#pragma unroll
        for (int n = 0; n < 4; ++n) acc[m][n] = 0.0f;

    // register prefetch buffers (next K-chunk)
    float4 px[4], pn[4], pw[4];

    // preload chunk 0
#pragma unroll
    for (int i = 0; i < 4; ++i) {
        const int f  = t + i * 256;          // float4 index within 64x16-f4 tile
        const int r  = f >> 4;
        const int c4 = f & 15;
        const size_t g = (size_t)(rowBase + r) * DIM + (size_t)(kOff + c4 * 4);
        px[i] = *(const float4*)(x + g);
        pn[i] = *(const float4*)(noise + g);
        pw[i] = *(const float4*)(W + (size_t)kOff * NEXP + (size_t)f * 4);
    }

    for (int kt = 0; kt < KCHUNKS; ++kt) {
        __syncthreads();  // previous chunk's readers done
#pragma unroll
        for (int i = 0; i < 4; ++i) {
            const int f  = t + i * 256;
            const int r  = f >> 4;
            const int c4 = f & 15;
            const float4 xv = px[i], nv = pn[i];
            float4 j;
            j.x = xv.x * (0.99f + 0.02f * nv.x);
            j.y = xv.y * (0.99f + 0.02f * nv.y);
            j.z = xv.z * (0.99f + 0.02f * nv.z);
            j.w = xv.w * (0.99f + 0.02f * nv.w);
            *(float4*)&xs[r * XS_STRIDE + c4 * 4] = j;
            *(float4*)&ws[f * 4] = pw[i];
        }
        __syncthreads();

        // issue next chunk's global loads before computing
        if (kt + 1 < KCHUNKS) {
            const int k0 = kOff + (kt + 1) * BK;
#pragma unroll
            for (int i = 0; i < 4; ++i) {
                const int f  = t + i * 256;
                const int r  = f >> 4;
                const int c4 = f & 15;
                const size_t g = (size_t)(rowBase + r) * DIM + (size_t)(k0 + c4 * 4);
                px[i] = *(const float4*)(x + g);
                pn[i] = *(const float4*)(noise + g);
                pw[i] = *(const float4*)(W + (size_t)k0 * NEXP + (size_t)f * 4);
            }
        }

        const float4* xs4 = (const float4*)xs;   // row stride = 17 float4
        const float4* ws4 = (const float4*)ws;   // kk stride  = 16 float4
#pragma unroll 4
        for (int kk4 = 0; kk4 < 16; ++kk4) {
            const float4 b0 = ws4[(kk4 * 4 + 0) * 16 + eg];
            const float4 b1 = ws4[(kk4 * 4 + 1) * 16 + eg];
            const float4 b2 = ws4[(kk4 * 4 + 2) * 16 + eg];
            const float4 b3 = ws4[(kk4 * 4 + 3) * 16 + eg];
#pragma unroll
            for (int m = 0; m < 4; ++m) {
                const float4 a = xs4[(rg * 4 + m) * 17 + kk4];
                acc[m][0] += a.x * b0.x; acc[m][1] += a.x * b0.y;
                acc[m][2] += a.x * b0.z; acc[m][3] += a.x * b0.w;
                acc[m][0] += a.y * b1.x; acc[m][1] += a.y * b1.y;
                acc[m][2] += a.y * b1.z; acc[m][3] += a.y * b1.w;
                acc[m][0] += a.z * b2.x; acc[m][1] += a.z * b2.y;
                acc[m][2] += a.z * b2.z; acc[m][3] += a.z * b2.w;
                acc[m][0] += a.w * b3.x; acc[m][1] += a.w * b3.y;
                acc[m][2] += a.w * b3.z; acc[m][3] += a.w * b3.w;
            }
        }
    }

    if (ATOMIC_OUT) {
#pragma unroll
        for (int m = 0; m < 4; ++m)
#pragma unroll
            for (int n = 0; n < 4; ++n)
                atomicAdd(out + (size_t)(rowBase + rg * 4 + m) * NEXP + eg * 4 + n,
                          acc[m][n]);
    } else {
        float* dst = out + (size_t)blockIdx.y * N_TOK * NEXP;
#pragma unroll
        for (int m = 0; m < 4; ++m) {
            float4 o;
            o.x = acc[m][0]; o.y = acc[m][1]; o.z = acc[m][2]; o.w = acc[m][3];
            *(float4*)(dst + (size_t)(rowBase + rg * 4 + m) * NEXP + eg * 4) = o;
        }
    }
}

// Thread-per-row router: 64 threads/block, 64 rows/block, 256 blocks.
// Phase A: cooperative coalesced load of [64 rows x 64 e] (summing KSPLIT
//          partials) -> logits global store + stride-65 LDS tile.
// Phase B: per-thread in-register softmax + biased top-8 (all static indexing).
// Phase C: cooperative coalesced scores store + histogram flush.
__global__ __launch_bounds__(64) void router_topk_kernel(
    const float* part, int nsplit, int writeLogits,
    const float* __restrict__ score_bias,
    float* logits, float* __restrict__ scores,
    float* __restrict__ weights, float* __restrict__ indicesF,
    float* __restrict__ histF)
{
    __shared__ float tile[64 * 65];   // stride 65: bank (l+j)%32, conflict-free
    __shared__ float bs[NEXP];
    __shared__ int   hist[NEXP];

    const int t = threadIdx.x;        // 0..63
    const int rowBase = blockIdx.x * 64;
    bs[t] = score_bias[t];
    hist[t] = 0;
    __syncthreads();

    const size_t sstride = (size_t)N_TOK * NEXP;

    // Phase A
#pragma unroll
    for (int i = 0; i < 16; ++i) {
        const int f   = t + i * 64;        // float4 id in [0,1024)
        const int row = f >> 4;
        const int c4  = f & 15;
        const size_t g = (size_t)(rowBase + row) * NEXP + (size_t)(c4 * 4);
        float4 v = *(const float4*)(part + g);
        for (int s = 1; s < nsplit; ++s) {
            const float4 p = *(const float4*)(part + (size_t)s * sstride + g);
            v.x += p.x; v.y += p.y; v.z += p.z; v.w += p.w;
        }
        if (writeLogits) *(float4*)(logits + g) = v;
        float* dst = &tile[row * 65 + c4 * 4];
        dst[0] = v.x; dst[1] = v.y; dst[2] = v.z; dst[3] = v.w;
    }
    __syncthreads();

    // Phase B: this thread owns row (rowBase + t)
    float a[NEXP];
#pragma unroll
    for (int j = 0; j < NEXP; ++j) a[j] = tile[t * 65 + j];

    // max (4 independent chains for ILP)
    float m0 = a[0], m1 = a[1], m2 = a[2], m3 = a[3];
#pragma unroll
    for (int j = 4; j < NEXP; j += 4) {
        m0 = fmaxf(m0, a[j + 0]); m1 = fmaxf(m1, a[j + 1]);
        m2 = fmaxf(m2, a[j + 2]); m3 = fmaxf(m3, a[j + 3]);
    }
    const float mx = fmaxf(fmaxf(m0, m1), fmaxf(m2, m3));

    // exp + sum
    float s0 = 0.f, s1 = 0.f, s2 = 0.f, s3 = 0.f;
#pragma unroll
    for (int j = 0; j < NEXP; j += 4) {
        a[j + 0] = expf(a[j + 0] - mx); s0 += a[j + 0];
        a[j + 1] = expf(a[j + 1] - mx); s1 += a[j + 1];
        a[j + 2] = expf(a[j + 2] - mx); s2 += a[j + 2];
        a[j + 3] = expf(a[j + 3] - mx); s3 += a[j + 3];
    }
    const float sinv = 1.0f / ((s0 + s1) + (s2 + s3));
#pragma unroll
    for (int j = 0; j < NEXP; ++j) a[j] *= sinv;       // a = scores

    // stash scores for coalesced store (own row only -> no cross-thread hazard)
#pragma unroll
    for (int j = 0; j < NEXP; ++j) tile[t * 65 + j] = a[j];

    // biased scores
#pragma unroll
    for (int j = 0; j < NEXP; ++j) a[j] += bs[j];

    // top-8: repeated argmax, ties -> lower index (strict > keeps lowest)
    float wv[TOPK]; int wi[TOPK];
    float ssq = 0.0f;
#pragma unroll
    for (int k = 0; k < TOPK; ++k) {
        float mA = a[0],  mB = a[16], mC = a[32], mD = a[48];
        int   iA = 0,     iB = 16,    iC = 32,    iD = 48;
#pragma unroll
        for (int j = 1; j < 16; ++j) {
            if (a[j]      > mA) { mA = a[j];      iA = j; }
            if (a[16 + j] > mB) { mB = a[16 + j]; iB = 16 + j; }
            if (a[32 + j] > mC) { mC = a[32 + j]; iC = 32 + j; }
            if (a[48 + j] > mD) { mD = a[48 + j]; iD = 48 + j; }
        }
        float m = mA; int mi = iA;
        if (mB > m) { m = mB; mi = iB; }
        if (mC > m) { m = mC; mi = iC; }
        if (mD > m) { m = mD; mi = iD; }

        const float w = m - bs[mi];   // unbiased score (exact when bias==0)
        wv[k] = w; wi[k] = mi; ssq += w * w;
        // invalidate winner (static-index cndmask, avoids reg-array scatter)
#pragma unroll
        for (int j = 0; j < NEXP; ++j) if (j == mi) a[j] = -INFINITY;
    }

    const float rn = 1.0f / sqrtf(ssq);
    const size_t ro = (size_t)(rowBase + t) * TOPK;
#pragma unroll
    for (int k = 0; k < TOPK; ++k) {
        weights[ro + k]  = wv[k] * rn;
        indicesF[ro + k] = (float)wi[k];
        atomicAdd(&hist[wi[k]], 1);
    }
    __syncthreads();

    // Phase C: coalesced scores store
#pragma unroll
    for (int i = 0; i < 16; ++i) {
        const int f   = t + i * 64;
        const int row = f >> 4;
        const int c4  = f & 15;
        const float* src = &tile[row * 65 + c4 * 4];
        float4 o; o.x = src[0]; o.y = src[1]; o.z = src[2]; o.w = src[3];
        *(float4*)(scores + (size_t)(rowBase + row) * NEXP + (size_t)(c4 * 4)) = o;
    }
    atomicAdd(&histF[t], (float)hist[t]);
}

extern "C" void kernel_launch(void* const* d_in, const int* in_sizes, int n_in,
                              void* d_out, int out_size, void* d_ws, size_t ws_size,
                              hipStream_t stream)
{
    const float* x     = (const float*)d_in[0];
    const float* W     = (const float*)d_in[1];
    const float* sbias = (const float*)d_in[2];
    const float* noise = (const float*)d_in[3];

    float* out      = (float*)d_out;
    float* logits   = out;                                    // 16384*64
    float* scores   = out + (size_t)N_TOK * NEXP;             // 16384*64
    float* weights  = out + 2ull * N_TOK * NEXP;              // 16384*8
    float* indicesF = weights + (size_t)N_TOK * TOPK;         // 16384*8
    float* histF    = indicesF + (size_t)N_TOK * TOPK;        // 64

    hipMemsetAsync(histF, 0, NEXP * sizeof(float), stream);   // capture-safe

    const size_t partialBytes = (size_t)KSPLIT * N_TOK * NEXP * sizeof(float); // 16 MB
    dim3 ggrid(N_TOK / BM, KSPLIT);

    if (d_ws != nullptr && ws_size >= partialBytes) {
        float* partial = (float*)d_ws;
        gemm_logits_kernel<0><<<ggrid, 256, 0, stream>>>(x, W, noise, partial);
        router_topk_kernel<<<N_TOK / 64, 64, 0, stream>>>(
            partial, KSPLIT, 1, sbias, logits, scores, weights, indicesF, histF);
    } else {
        // fallback: accumulate splits directly into logits via atomics
        hipMemsetAsync(logits, 0, (size_t)N_TOK * NEXP * sizeof(float), stream);
        gemm_logits_kernel<1><<<ggrid, 256, 0, stream>>>(x, W, noise, logits);
        router_topk_kernel<<<N_TOK / 64, 64, 0, stream>>>(
            logits, 1, 0, sbias, logits, scores, weights, indicesF, histF);
    }
}

// Round 2
// 626.299 us; speedup vs baseline: 1.2851x; 1.0094x over previous
//
#include <hip/hip_runtime.h>
#include <math.h>

// MoE router: N=16384 tokens, D=4096, E=64 experts, top-8.
// Kernel 1: logits = (x * (0.99 + 0.02*noise)) @ W -- f32, split-K x4.
//   __launch_bounds__(256, 4): 4 waves/SIMD -> VGPR cap 128. Without the
//   min-waves hint the compiler capped at 60 VGPRs and spilled the float4
//   prefetch buffers to scratch (observed: WRITE_SIZE 197 MB vs 16 MB expected).
// Kernel 2: thread-per-row softmax + biased top-8 in registers.
//   __launch_bounds__(64, 1): VGPR cap 512 so a[64] stays in registers.

#define N_TOK 16384
#define DIM   4096
#define NEXP  64
#define TOPK  8

#define BM 64
#define BK 64
#define KSPLIT 4
#define KCHUNKS (DIM / (BK * KSPLIT))   // 16 chunks per block
#define XS_STRIDE 68                    // 64 + 4 pad, keeps 16B alignment

// ATOMIC_OUT=0: store partial[blockIdx.y][row][e] to workspace (no atomics)
// ATOMIC_OUT=1: atomicAdd into pre-zeroed logits (fallback if ws too small)
template<int ATOMIC_OUT>
__global__ __launch_bounds__(256, 4) void gemm_logits_kernel(
    const float* __restrict__ x, const float* __restrict__ W,
    const float* __restrict__ noise, float* __restrict__ out)
{
    __shared__ float xs[BM * XS_STRIDE];  // 17408 B
    __shared__ float ws[BK * NEXP];       // 16384 B  -> 33792 B total, 4 blocks/CU

    const int t = threadIdx.x;
    const int rowBase = blockIdx.x * BM;
    const int kOff = blockIdx.y * (DIM / KSPLIT);   // split-K offset
    const int eg = t & 15;   // experts eg*4 .. eg*4+3
    const int rg = t >> 4;   // rows    rg*4 .. rg*4+3

    float acc[4][4];
#pragma unroll
    for (int m = 0; m < 4; ++m)
#pragma unroll
        for (int n = 0; n < 4; ++n) acc[m][n] = 0.0f;

    // register prefetch buffers (next K-chunk) -- must stay in VGPRs!
    float4 px[4], pn[4], pw[4];

    // preload chunk 0
#pragma unroll
    for (int i = 0; i < 4; ++i) {
        const int f  = t + i * 256;          // float4 index within 64x16-f4 tile
        const int r  = f >> 4;
        const int c4 = f & 15;
        const size_t g = (size_t)(rowBase + r) * DIM + (size_t)(kOff + c4 * 4);
        px[i] = *(const float4*)(x + g);
        pn[i] = *(const float4*)(noise + g);
        pw[i] = *(const float4*)(W + (size_t)kOff * NEXP + (size_t)f * 4);
    }

    for (int kt = 0; kt < KCHUNKS; ++kt) {
        __syncthreads();  // previous chunk's readers done
#pragma unroll
        for (int i = 0; i < 4; ++i) {
            const int f  = t + i * 256;
            const int r  = f >> 4;
            const int c4 = f & 15;
            const float4 xv = px[i], nv = pn[i];
            float4 j;
            j.x = xv.x * (0.99f + 0.02f * nv.x);
            j.y = xv.y * (0.99f + 0.02f * nv.y);
            j.z = xv.z * (0.99f + 0.02f * nv.z);
            j.w = xv.w * (0.99f + 0.02f * nv.w);
            *(float4*)&xs[r * XS_STRIDE + c4 * 4] = j;
            *(float4*)&ws[f * 4] = pw[i];
        }
        __syncthreads();

        // issue next chunk's global loads before computing
        if (kt + 1 < KCHUNKS) {
            const int k0 = kOff + (kt + 1) * BK;
#pragma unroll
            for (int i = 0; i < 4; ++i) {
                const int f  = t + i * 256;
                const int r  = f >> 4;
                const int c4 = f & 15;
                const size_t g = (size_t)(rowBase + r) * DIM + (size_t)(k0 + c4 * 4);
                px[i] = *(const float4*)(x + g);
                pn[i] = *(const float4*)(noise + g);
                pw[i] = *(const float4*)(W + (size_t)k0 * NEXP + (size_t)f * 4);
            }
        }

        const float4* xs4 = (const float4*)xs;   // row stride = 17 float4
        const float4* ws4 = (const float4*)ws;   // kk stride  = 16 float4
#pragma unroll 4
        for (int kk4 = 0; kk4 < 16; ++kk4) {
            const float4 b0 = ws4[(kk4 * 4 + 0) * 16 + eg];
            const float4 b1 = ws4[(kk4 * 4 + 1) * 16 + eg];
            const float4 b2 = ws4[(kk4 * 4 + 2) * 16 + eg];
            const float4 b3 = ws4[(kk4 * 4 + 3) * 16 + eg];
#pragma unroll
            for (int m = 0; m < 4; ++m) {
                const float4 a = xs4[(rg * 4 + m) * 17 + kk4];
                acc[m][0] += a.x * b0.x; acc[m][1] += a.x * b0.y;
                acc[m][2] += a.x * b0.z; acc[m][3] += a.x * b0.w;
                acc[m][0] += a.y * b1.x; acc[m][1] += a.y * b1.y;
                acc[m][2] += a.y * b1.z; acc[m][3] += a.y * b1.w;
                acc[m][0] += a.z * b2.x; acc[m][1] += a.z * b2.y;
                acc[m][2] += a.z * b2.z; acc[m][3] += a.z * b2.w;
                acc[m][0] += a.w * b3.x; acc[m][1] += a.w * b3.y;
                acc[m][2] += a.w * b3.z; acc[m][3] += a.w * b3.w;
            }
        }
    }

    if (ATOMIC_OUT) {
#pragma unroll
        for (int m = 0; m < 4; ++m)
#pragma unroll
            for (int n = 0; n < 4; ++n)
                atomicAdd(out + (size_t)(rowBase + rg * 4 + m) * NEXP + eg * 4 + n,
                          acc[m][n]);
    } else {
        float* dst = out + (size_t)blockIdx.y * N_TOK * NEXP;
#pragma unroll
        for (int m = 0; m < 4; ++m) {
            float4 o;
            o.x = acc[m][0]; o.y = acc[m][1]; o.z = acc[m][2]; o.w = acc[m][3];
            *(float4*)(dst + (size_t)(rowBase + rg * 4 + m) * NEXP + eg * 4) = o;
        }
    }
}

// Thread-per-row router: 64 threads/block, 64 rows/block, 256 blocks.
// Phase A: cooperative coalesced load of [64 rows x 64 e] (summing KSPLIT
//          partials) -> logits global store + stride-65 LDS tile.
// Phase B: per-thread in-register softmax + biased top-8 (all static indexing).
// Phase C: cooperative coalesced scores store + histogram flush.
__global__ __launch_bounds__(64, 1) void router_topk_kernel(
    const float* part, int nsplit, int writeLogits,
    const float* __restrict__ score_bias,
    float* logits, float* __restrict__ scores,
    float* __restrict__ weights, float* __restrict__ indicesF,
    float* __restrict__ histF)
{
    __shared__ float tile[64 * 65];   // stride 65: bank (l+j)%32, conflict-free
    __shared__ float bs[NEXP];
    __shared__ int   hist[NEXP];

    const int t = threadIdx.x;        // 0..63
    const int rowBase = blockIdx.x * 64;
    bs[t] = score_bias[t];
    hist[t] = 0;
    __syncthreads();

    const size_t sstride = (size_t)N_TOK * NEXP;

    // Phase A
#pragma unroll
    for (int i = 0; i < 16; ++i) {
        const int f   = t + i * 64;        // float4 id in [0,1024)
        const int row = f >> 4;
        const int c4  = f & 15;
        const size_t g = (size_t)(rowBase + row) * NEXP + (size_t)(c4 * 4);
        float4 v = *(const float4*)(part + g);
        for (int s = 1; s < nsplit; ++s) {
            const float4 p = *(const float4*)(part + (size_t)s * sstride + g);
            v.x += p.x; v.y += p.y; v.z += p.z; v.w += p.w;
        }
        if (writeLogits) *(float4*)(logits + g) = v;
        float* dst = &tile[row * 65 + c4 * 4];
        dst[0] = v.x; dst[1] = v.y; dst[2] = v.z; dst[3] = v.w;
    }
    __syncthreads();

    // Phase B: this thread owns row (rowBase + t)
    float a[NEXP];
#pragma unroll
    for (int j = 0; j < NEXP; ++j) a[j] = tile[t * 65 + j];

    // max (4 independent chains for ILP)
    float m0 = a[0], m1 = a[1], m2 = a[2], m3 = a[3];
#pragma unroll
    for (int j = 4; j < NEXP; j += 4) {
        m0 = fmaxf(m0, a[j + 0]); m1 = fmaxf(m1, a[j + 1]);
        m2 = fmaxf(m2, a[j + 2]); m3 = fmaxf(m3, a[j + 3]);
    }
    const float mx = fmaxf(fmaxf(m0, m1), fmaxf(m2, m3));

    // exp + sum
    float s0 = 0.f, s1 = 0.f, s2 = 0.f, s3 = 0.f;
#pragma unroll
    for (int j = 0; j < NEXP; j += 4) {
        a[j + 0] = expf(a[j + 0] - mx); s0 += a[j + 0];
        a[j + 1] = expf(a[j + 1] - mx); s1 += a[j + 1];
        a[j + 2] = expf(a[j + 2] - mx); s2 += a[j + 2];
        a[j + 3] = expf(a[j + 3] - mx); s3 += a[j + 3];
    }
    const float sinv = 1.0f / ((s0 + s1) + (s2 + s3));
#pragma unroll
    for (int j = 0; j < NEXP; ++j) a[j] *= sinv;       // a = scores

    // stash scores for coalesced store + exact unbiased gather
#pragma unroll
    for (int j = 0; j < NEXP; ++j) tile[t * 65 + j] = a[j];

    // biased scores
#pragma unroll
    for (int j = 0; j < NEXP; ++j) a[j] += bs[j];

    // top-8: repeated argmax, ties -> lower index (strict > keeps lowest)
    float wv[TOPK]; int wi[TOPK];
    float ssq = 0.0f;
#pragma unroll
    for (int k = 0; k < TOPK; ++k) {
        float mA = a[0],  mB = a[16], mC = a[32], mD = a[48];
        int   iA = 0,     iB = 16,    iC = 32,    iD = 48;
#pragma unroll
        for (int j = 1; j < 16; ++j) {
            if (a[j]      > mA) { mA = a[j];      iA = j; }
            if (a[16 + j] > mB) { mB = a[16 + j]; iB = 16 + j; }
            if (a[32 + j] > mC) { mC = a[32 + j]; iC = 32 + j; }
            if (a[48 + j] > mD) { mD = a[48 + j]; iD = 48 + j; }
        }
        float m = mA; int mi = iA;
        if (mB > m) { m = mB; mi = iB; }
        if (mC > m) { m = mC; mi = iC; }
        if (mD > m) { m = mD; mi = iD; }

        const float w = tile[t * 65 + mi];   // unbiased score (exact, LDS gather)
        wv[k] = w; wi[k] = mi; ssq += w * w;
        // invalidate winner (static-index cndmask, avoids reg-array scatter)
#pragma unroll
        for (int j = 0; j < NEXP; ++j) if (j == mi) a[j] = -INFINITY;
    }

    const float rn = 1.0f / sqrtf(ssq);
    const size_t ro = (size_t)(rowBase + t) * TOPK;
#pragma unroll
    for (int k = 0; k < TOPK; ++k) {
        weights[ro + k]  = wv[k] * rn;
        indicesF[ro + k] = (float)wi[k];
        atomicAdd(&hist[wi[k]], 1);
    }
    __syncthreads();

    // Phase C: coalesced scores store
#pragma unroll
    for (int i = 0; i < 16; ++i) {
        const int f   = t + i * 64;
        const int row = f >> 4;
        const int c4  = f & 15;
        const float* src = &tile[row * 65 + c4 * 4];
        float4 o; o.x = src[0]; o.y = src[1]; o.z = src[2]; o.w = src[3];
        *(float4*)(scores + (size_t)(rowBase + row) * NEXP + (size_t)(c4 * 4)) = o;
    }
    atomicAdd(&histF[t], (float)hist[t]);
}

extern "C" void kernel_launch(void* const* d_in, const int* in_sizes, int n_in,
                              void* d_out, int out_size, void* d_ws, size_t ws_size,
                              hipStream_t stream)
{
    const float* x     = (const float*)d_in[0];
    const float* W     = (const float*)d_in[1];
    const float* sbias = (const float*)d_in[2];
    const float* noise = (const float*)d_in[3];

    float* out      = (float*)d_out;
    float* logits   = out;                                    // 16384*64
    float* scores   = out + (size_t)N_TOK * NEXP;             // 16384*64
    float* weights  = out + 2ull * N_TOK * NEXP;              // 16384*8
    float* indicesF = weights + (size_t)N_TOK * TOPK;         // 16384*8
    float* histF    = indicesF + (size_t)N_TOK * TOPK;        // 64

    hipMemsetAsync(histF, 0, NEXP * sizeof(float), stream);   // capture-safe

    const size_t partialBytes = (size_t)KSPLIT * N_TOK * NEXP * sizeof(float); // 16 MB
    dim3 ggrid(N_TOK / BM, KSPLIT);

    if (d_ws != nullptr && ws_size >= partialBytes) {
        float* partial = (float*)d_ws;
        gemm_logits_kernel<0><<<ggrid, 256, 0, stream>>>(x, W, noise, partial);
        router_topk_kernel<<<N_TOK / 64, 64, 0, stream>>>(
            partial, KSPLIT, 1, sbias, logits, scores, weights, indicesF, histF);
    } else {
        // fallback: accumulate splits directly into logits via atomics
        hipMemsetAsync(logits, 0, (size_t)N_TOK * NEXP * sizeof(float), stream);
        gemm_logits_kernel<1><<<ggrid, 256, 0, stream>>>(x, W, noise, logits);
        router_topk_kernel<<<N_TOK / 64, 64, 0, stream>>>(
            logits, 1, 0, sbias, logits, scores, weights, indicesF, histF);
    }
}

// Round 5
// 580.891 us; speedup vs baseline: 1.3855x; 1.0782x over previous
//
#include <hip/hip_runtime.h>
#include <math.h>

// MoE router: N=16384 tokens, D=4096, E=64 experts, top-8.
// Kernel 1 (v3b): logits = (x * (0.99 + 0.02*noise)) @ W, f32, split-K x4.
//   BK=32, double-buffered LDS (32 KB) -> 4 blocks/CU resident (16 waves/CU).
//   Per-thread 2x8 register tile; jitter applied at stage time (noise never
//   enters LDS). Stage set = 6 float4 (24 VGPR). x-tile XOR-swizzled
//   (col ^= (row>>1)&7) -- linear layout would be an 8-way read conflict.
//   v3b: flattened (no lambdas, no sched_barrier) after two container
//   failures on v3; algorithm identical.
// Kernel 2: thread-per-row softmax + biased top-8 in registers (unchanged,
//   ran correctly in round 2).

#define N_TOK 16384
#define DIM   4096
#define NEXP  64
#define TOPK  8

#define BM 64
#define BK 32
#define KSPLIT 4
#define KPERSPLIT (DIM / KSPLIT)    // 1024
#define NCH (KPERSPLIT / BK)        // 32 chunks per block

// Issue global loads for chunk KT into px/pn/pwv (2 float4 each)
#define ISSUE_LOADS(KT)                                                     \
    {                                                                       \
        const int k0_ = kOff + (KT) * BK;                                   \
        _Pragma("unroll")                                                   \
        for (int i_ = 0; i_ < 2; ++i_) {                                    \
            const int f_ = i_ * 256 + t;                                    \
            const int r_ = f_ >> 3;                                         \
            const int c_ = f_ & 7;                                          \
            const size_t g_ = (size_t)(rowBase + r_) * DIM                  \
                            + (size_t)(k0_ + c_ * 4);                       \
            px[i_]  = *(const float4*)(x + g_);                             \
            pn[i_]  = *(const float4*)(noise + g_);                         \
            pwv[i_] = *(const float4*)(W + (size_t)k0_ * NEXP               \
                                         + (size_t)f_ * 4);                 \
        }                                                                   \
    }

// Jitter + stage px/pn/pwv into LDS buffer B
#define STAGE(B)                                                            \
    {                                                                       \
        _Pragma("unroll")                                                   \
        for (int i_ = 0; i_ < 2; ++i_) {                                    \
            const int f_ = i_ * 256 + t;                                    \
            const int r_ = f_ >> 3;                                         \
            const int c_ = f_ & 7;                                          \
            const float4 xv_ = px[i_], nv_ = pn[i_];                        \
            float4 j_;                                                      \
            j_.x = xv_.x * (0.99f + 0.02f * nv_.x);                         \
            j_.y = xv_.y * (0.99f + 0.02f * nv_.y);                         \
            j_.z = xv_.z * (0.99f + 0.02f * nv_.z);                         \
            j_.w = xv_.w * (0.99f + 0.02f * nv_.w);                         \
            const int slot_ = r_ * 8 + (c_ ^ ((r_ >> 1) & 7));              \
            *(float4*)&xs[B][slot_ * 4] = j_;                               \
            *(float4*)&ws[B][f_ * 4]    = pwv[i_];                          \
        }                                                                   \
    }

// ATOMIC_OUT=0: store partial[blockIdx.y][row][e] to workspace (no atomics)
// ATOMIC_OUT=1: atomicAdd into pre-zeroed logits (fallback if ws too small)
template<int ATOMIC_OUT>
__global__ __launch_bounds__(256, 4) void gemm_logits_kernel(
    const float* __restrict__ x, const float* __restrict__ W,
    const float* __restrict__ noise, float* __restrict__ out)
{
    __shared__ float xs[2][BM * BK];    // 2 x 8 KB, jittered x (swizzled)
    __shared__ float ws[2][BK * NEXP];  // 2 x 8 KB, W tile (linear)

    const int t = threadIdx.x;
    const int rowBase = blockIdx.x * BM;
    const int kOff = blockIdx.y * KPERSPLIT;
    const int eg = t & 7;    // expert octet: experts eg*8 .. eg*8+7
    const int rg = t >> 3;   // row pair:    rows    rg*2, rg*2+1
    const int eg2 = eg * 2;  // float4 offset within a k-row of ws

    float acc[2][8];
#pragma unroll
    for (int m = 0; m < 2; ++m)
#pragma unroll
        for (int n = 0; n < 8; ++n) acc[m][n] = 0.0f;

    float4 px[2], pn[2], pwv[2];   // stage registers (24 VGPRs)

    // prologue: fill buffer 0
    ISSUE_LOADS(0)
    STAGE(0)

    for (int kt = 0; kt < NCH; ++kt) {
        const int cb = kt & 1;
        __syncthreads();                 // publish buf cb
        if (kt + 1 < NCH) {
            ISSUE_LOADS(kt + 1)          // HBM latency hides under compute
        }

        const float4* xs4 = (const float4*)xs[cb];
        const float4* ws4 = (const float4*)ws[cb];
        const int r0 = rg * 2;
        const int sw = rg & 7;           // == ((r0>>1)&7), same for r0+1

#pragma unroll
        for (int kk4 = 0; kk4 < 8; ++kk4) {
            const float4 a0 = xs4[(r0 + 0) * 8 + (kk4 ^ sw)];
            const float4 a1 = xs4[(r0 + 1) * 8 + (kk4 ^ sw)];
#define KSTEP(q, A0Q, A1Q)                                                  \
            {                                                               \
                const float4 b0 = ws4[(kk4 * 4 + q) * 16 + eg2];            \
                const float4 b1 = ws4[(kk4 * 4 + q) * 16 + eg2 + 1];        \
                acc[0][0] += A0Q * b0.x; acc[0][1] += A0Q * b0.y;           \
                acc[0][2] += A0Q * b0.z; acc[0][3] += A0Q * b0.w;           \
                acc[0][4] += A0Q * b1.x; acc[0][5] += A0Q * b1.y;           \
                acc[0][6] += A0Q * b1.z; acc[0][7] += A0Q * b1.w;           \
                acc[1][0] += A1Q * b0.x; acc[1][1] += A1Q * b0.y;           \
                acc[1][2] += A1Q * b0.z; acc[1][3] += A1Q * b0.w;           \
                acc[1][4] += A1Q * b1.x; acc[1][5] += A1Q * b1.y;           \
                acc[1][6] += A1Q * b1.z; acc[1][7] += A1Q * b1.w;           \
            }
            KSTEP(0, a0.x, a1.x)
            KSTEP(1, a0.y, a1.y)
            KSTEP(2, a0.z, a1.z)
            KSTEP(3, a0.w, a1.w)
#undef KSTEP
        }

        if (kt + 1 < NCH) {
            STAGE(cb ^ 1)  // safe: buf cb^1's readers finished before the
        }                  // barrier at the top of this iteration
    }

    // epilogue
    if (ATOMIC_OUT) {
#pragma unroll
        for (int m = 0; m < 2; ++m)
#pragma unroll
            for (int n = 0; n < 8; ++n)
                atomicAdd(out + (size_t)(rowBase + rg * 2 + m) * NEXP + eg * 8 + n,
                          acc[m][n]);
    } else {
        float* dst = out + (size_t)blockIdx.y * N_TOK * NEXP;
#pragma unroll
        for (int m = 0; m < 2; ++m) {
            float4 o0, o1;
            o0.x = acc[m][0]; o0.y = acc[m][1]; o0.z = acc[m][2]; o0.w = acc[m][3];
            o1.x = acc[m][4]; o1.y = acc[m][5]; o1.z = acc[m][6]; o1.w = acc[m][7];
            float* rowp = dst + (size_t)(rowBase + rg * 2 + m) * NEXP + eg * 8;
            *(float4*)(rowp)     = o0;
            *(float4*)(rowp + 4) = o1;
        }
    }
}

// Thread-per-row router: 64 threads/block, 64 rows/block, 256 blocks.
__global__ __launch_bounds__(64, 1) void router_topk_kernel(
    const float* part, int nsplit, int writeLogits,
    const float* __restrict__ score_bias,
    float* logits, float* __restrict__ scores,
    float* __restrict__ weights, float* __restrict__ indicesF,
    float* __restrict__ histF)
{
    __shared__ float tile[64 * 65];   // stride 65: conflict-free
    __shared__ float bs[NEXP];
    __shared__ int   hist[NEXP];

    const int t = threadIdx.x;        // 0..63
    const int rowBase = blockIdx.x * 64;
    bs[t] = score_bias[t];
    hist[t] = 0;
    __syncthreads();

    const size_t sstride = (size_t)N_TOK * NEXP;

    // Phase A: coalesced load (+split reduce) -> logits store + LDS tile
#pragma unroll
    for (int i = 0; i < 16; ++i) {
        const int f   = t + i * 64;
        const int row = f >> 4;
        const int c4  = f & 15;
        const size_t g = (size_t)(rowBase + row) * NEXP + (size_t)(c4 * 4);
        float4 v = *(const float4*)(part + g);
        for (int s = 1; s < nsplit; ++s) {
            const float4 p = *(const float4*)(part + (size_t)s * sstride + g);
            v.x += p.x; v.y += p.y; v.z += p.z; v.w += p.w;
        }
        if (writeLogits) *(float4*)(logits + g) = v;
        float* dst = &tile[row * 65 + c4 * 4];
        dst[0] = v.x; dst[1] = v.y; dst[2] = v.z; dst[3] = v.w;
    }
    __syncthreads();

    // Phase B: this thread owns row (rowBase + t)
    float a[NEXP];
#pragma unroll
    for (int j = 0; j < NEXP; ++j) a[j] = tile[t * 65 + j];

    float m0 = a[0], m1 = a[1], m2 = a[2], m3 = a[3];
#pragma unroll
    for (int j = 4; j < NEXP; j += 4) {
        m0 = fmaxf(m0, a[j + 0]); m1 = fmaxf(m1, a[j + 1]);
        m2 = fmaxf(m2, a[j + 2]); m3 = fmaxf(m3, a[j + 3]);
    }
    const float mx = fmaxf(fmaxf(m0, m1), fmaxf(m2, m3));

    float s0 = 0.f, s1 = 0.f, s2 = 0.f, s3 = 0.f;
#pragma unroll
    for (int j = 0; j < NEXP; j += 4) {
        a[j + 0] = expf(a[j + 0] - mx); s0 += a[j + 0];
        a[j + 1] = expf(a[j + 1] - mx); s1 += a[j + 1];
        a[j + 2] = expf(a[j + 2] - mx); s2 += a[j + 2];
        a[j + 3] = expf(a[j + 3] - mx); s3 += a[j + 3];
    }
    const float sinv = 1.0f / ((s0 + s1) + (s2 + s3));
#pragma unroll
    for (int j = 0; j < NEXP; ++j) a[j] *= sinv;       // a = scores

#pragma unroll
    for (int j = 0; j < NEXP; ++j) tile[t * 65 + j] = a[j];

#pragma unroll
    for (int j = 0; j < NEXP; ++j) a[j] += bs[j];      // biased

    float wv[TOPK]; int wi[TOPK];
    float ssq = 0.0f;
#pragma unroll
    for (int k = 0; k < TOPK; ++k) {
        float mA = a[0],  mB = a[16], mC = a[32], mD = a[48];
        int   iA = 0,     iB = 16,    iC = 32,    iD = 48;
#pragma unroll
        for (int j = 1; j < 16; ++j) {
            if (a[j]      > mA) { mA = a[j];      iA = j; }
            if (a[16 + j] > mB) { mB = a[16 + j]; iB = 16 + j; }
            if (a[32 + j] > mC) { mC = a[32 + j]; iC = 32 + j; }
            if (a[48 + j] > mD) { mD = a[48 + j]; iD = 48 + j; }
        }
        float m = mA; int mi = iA;
        if (mB > m) { m = mB; mi = iB; }
        if (mC > m) { m = mC; mi = iC; }
        if (mD > m) { m = mD; mi = iD; }

        const float w = tile[t * 65 + mi];   // unbiased score (exact)
        wv[k] = w; wi[k] = mi; ssq += w * w;
#pragma unroll
        for (int j = 0; j < NEXP; ++j) if (j == mi) a[j] = -INFINITY;
    }

    const float rn = 1.0f / sqrtf(ssq);
    const size_t ro = (size_t)(rowBase + t) * TOPK;
#pragma unroll
    for (int k = 0; k < TOPK; ++k) {
        weights[ro + k]  = wv[k] * rn;
        indicesF[ro + k] = (float)wi[k];
        atomicAdd(&hist[wi[k]], 1);
    }
    __syncthreads();

    // Phase C: coalesced scores store
#pragma unroll
    for (int i = 0; i < 16; ++i) {
        const int f   = t + i * 64;
        const int row = f >> 4;
        const int c4  = f & 15;
        const float* src = &tile[row * 65 + c4 * 4];
        float4 o; o.x = src[0]; o.y = src[1]; o.z = src[2]; o.w = src[3];
        *(float4*)(scores + (size_t)(rowBase + row) * NEXP + (size_t)(c4 * 4)) = o;
    }
    atomicAdd(&histF[t], (float)hist[t]);
}

extern "C" void kernel_launch(void* const* d_in, const int* in_sizes, int n_in,
                              void* d_out, int out_size, void* d_ws, size_t ws_size,
                              hipStream_t stream)
{
    const float* x     = (const float*)d_in[0];
    const float* W     = (const float*)d_in[1];
    const float* sbias = (const float*)d_in[2];
    const float* noise = (const float*)d_in[3];

    float* out      = (float*)d_out;
    float* logits   = out;                                    // 16384*64
    float* scores   = out + (size_t)N_TOK * NEXP;             // 16384*64
    float* weights  = out + 2ull * N_TOK * NEXP;              // 16384*8
    float* indicesF = weights + (size_t)N_TOK * TOPK;         // 16384*8
    float* histF    = indicesF + (size_t)N_TOK * TOPK;        // 64

    hipMemsetAsync(histF, 0, NEXP * sizeof(float), stream);   // capture-safe

    const size_t partialBytes = (size_t)KSPLIT * N_TOK * NEXP * sizeof(float); // 16 MB
    dim3 ggrid(N_TOK / BM, KSPLIT);

    if (d_ws != nullptr && ws_size >= partialBytes) {
        float* partial = (float*)d_ws;
        gemm_logits_kernel<0><<<ggrid, 256, 0, stream>>>(x, W, noise, partial);
        router_topk_kernel<<<N_TOK / 64, 64, 0, stream>>>(
            partial, KSPLIT, 1, sbias, logits, scores, weights, indicesF, histF);
    } else {
        // fallback: accumulate splits directly into logits via atomics
        hipMemsetAsync(logits, 0, (size_t)N_TOK * NEXP * sizeof(float), stream);
        gemm_logits_kernel<1><<<ggrid, 256, 0, stream>>>(x, W, noise, logits);
        router_topk_kernel<<<N_TOK / 64, 64, 0, stream>>>(
            logits, 1, 0, sbias, logits, scores, weights, indicesF, histF);
    }
}